// Round 2
// baseline (864.558 us; speedup 1.0000x reference)
//
#include <hip/hip_runtime.h>

// GCN: 3 layers of {h = o@W; agg = Dinv A Dinv h (with self loops); BN+ReLU}, JK concat.
// N=50000, E=800000, D=128, L=3. All fp32.
//
// ws layout (~33 MB): cnt[N] cur[N] rowptr[N+1] blksum[64] colpk[E](int2)
//                     dinv[N] stats[256] scaleshift[256] h[N*128]

#define EPS_BN 1e-5f

__global__ void k_zero_i32(int* __restrict__ p, int n){
  int i = blockIdx.x*256 + threadIdx.x;
  if (i < n) p[i] = 0;
}
__global__ void k_zero_f32(float* __restrict__ p, int n){
  int i = blockIdx.x*256 + threadIdx.x;
  if (i < n) p[i] = 0.f;
}

__global__ void k_count(const int* __restrict__ dst, int* __restrict__ cnt, int E){
  int i = blockIdx.x*256 + threadIdx.x;
  if (i < E) atomicAdd(&cnt[dst[i]], 1);
}

__global__ void k_dinv(const int* __restrict__ cnt, float* __restrict__ dinv, int n){
  int i = blockIdx.x*256 + threadIdx.x;
  if (i < n) dinv[i] = rsqrtf((float)cnt[i] + 1.0f);  // +1 = self loop
}

// exclusive scan of cnt[N] -> rowptr[N], 1024 elems/block
__global__ void k_scan1(const int* __restrict__ in, int* __restrict__ out,
                        int* __restrict__ blksum, int n){
  __shared__ int sh[256];
  int t = threadIdx.x;
  int base = blockIdx.x*1024 + t*4;
  int v[4];
  #pragma unroll
  for (int j=0;j<4;j++) v[j] = (base+j < n) ? in[base+j] : 0;
  int tsum = v[0]+v[1]+v[2]+v[3];
  sh[t] = tsum;
  __syncthreads();
  #pragma unroll
  for (int off=1; off<256; off<<=1){
    int x = (t>=off) ? sh[t-off] : 0;
    __syncthreads();
    sh[t] += x;
    __syncthreads();
  }
  if (t==255) blksum[blockIdx.x] = sh[255];
  int run = sh[t] - tsum;
  #pragma unroll
  for (int j=0;j<4;j++){ if (base+j < n) out[base+j] = run; run += v[j]; }
}

__global__ void k_scan2(int* __restrict__ blksum, int nb){
  if (threadIdx.x == 0){
    int run = 0;
    for (int i=0;i<nb;i++){ int v = blksum[i]; blksum[i] = run; run += v; }
  }
}

__global__ void k_scan3(int* __restrict__ out, const int* __restrict__ blksum,
                        int n, int total){
  int i = blockIdx.x*256 + threadIdx.x;
  if (i < n) out[i] += blksum[i >> 10];
  if (i == 0) out[n] = total;
}

__global__ void k_fill(const int* __restrict__ src, const int* __restrict__ dst,
                       const float* __restrict__ dinv, const int* __restrict__ rowptr,
                       int* __restrict__ cur, int2* __restrict__ colpk, int E){
  int e = blockIdx.x*256 + threadIdx.x;
  if (e < E){
    int d = dst[e];
    int pos = rowptr[d] + atomicAdd(&cur[d], 1);
    int s = src[e];
    colpk[pos] = make_int2(s, __float_as_int(dinv[s]));
  }
}

__global__ void k_copyx(const float4* __restrict__ x, float* __restrict__ out, int n4){
  int i = blockIdx.x*256 + threadIdx.x;
  if (i < n4){
    int v = i >> 5, f4 = i & 31;
    ((float4*)(out + (size_t)v*512))[f4] = x[i];
  }
}

// h[N,128] = A[N,128](lda=512) @ W[128,128].  W fully in LDS (64KB).
// Block: 64 rows x 128 cols, 256 threads, each thread 4 rows x 8 cols.
__launch_bounds__(256)
__global__ void k_gemm(const float* __restrict__ A, const float* __restrict__ W,
                       float* __restrict__ H, int n){
  __shared__ float4 Wl[4096];          // 64KB
  const float4* W4 = (const float4*)W;
  #pragma unroll
  for (int j=0;j<16;j++) Wl[threadIdx.x + j*256] = W4[threadIdx.x + j*256];
  __syncthreads();

  const int t  = threadIdx.x;
  const int cx = t & 15;
  const int ry = t >> 4;
  const int r0 = blockIdx.x*64 + ry*4;

  float acc[4][8];
  #pragma unroll
  for (int a=0;a<4;a++)
    #pragma unroll
    for (int b=0;b<8;b++) acc[a][b] = 0.f;

  const float4* Arow[4];
  #pragma unroll
  for (int rr=0;rr<4;rr++){
    int r = r0 + rr; if (r > n-1) r = n-1;
    Arow[rr] = (const float4*)(A + (size_t)r*512);
  }
  const int cb = cx*2;

  for (int k4=0;k4<32;k4++){
    float4 a0 = Arow[0][k4], a1 = Arow[1][k4], a2 = Arow[2][k4], a3 = Arow[3][k4];
    #pragma unroll
    for (int kk=0;kk<4;kk++){
      int k = k4*4 + kk;
      float4 w0 = Wl[k*32 + cb];
      float4 w1 = Wl[k*32 + cb + 1];
      float av0 = ((const float*)&a0)[kk];
      float av1 = ((const float*)&a1)[kk];
      float av2 = ((const float*)&a2)[kk];
      float av3 = ((const float*)&a3)[kk];
      float wv[8] = {w0.x,w0.y,w0.z,w0.w,w1.x,w1.y,w1.z,w1.w};
      #pragma unroll
      for (int c=0;c<8;c++){
        acc[0][c] = fmaf(av0, wv[c], acc[0][c]);
        acc[1][c] = fmaf(av1, wv[c], acc[1][c]);
        acc[2][c] = fmaf(av2, wv[c], acc[2][c]);
        acc[3][c] = fmaf(av3, wv[c], acc[3][c]);
      }
    }
  }
  #pragma unroll
  for (int rr=0;rr<4;rr++){
    int r = r0 + rr;
    if (r < n){
      float4* Hp = (float4*)(H + (size_t)r*128 + cx*8);
      Hp[0] = make_float4(acc[rr][0],acc[rr][1],acc[rr][2],acc[rr][3]);
      Hp[1] = make_float4(acc[rr][4],acc[rr][5],acc[rr][6],acc[rr][7]);
    }
  }
}

// Pull-based aggregation + fused BN-stats partial sums.
// 256 threads = 8 node-slots x 32 lanes; each lane owns a float4 (4 features).
// Per edge: one broadcast int2 load + one coalesced 512B row gather.
__launch_bounds__(256)
__global__ void k_agg(const float4* __restrict__ h4, const int* __restrict__ rowptr,
                      const int2* __restrict__ colpk,
                      const float* __restrict__ dinv, float* __restrict__ out,
                      int colOff, float* __restrict__ stats, int n){
  __shared__ float ssum[256];          // [0:128)=sum, [128:256)=sumsq per feature
  ssum[threadIdx.x] = 0.f;
  __syncthreads();

  const int c    = threadIdx.x & 31;   // float4 index: features c*4 .. c*4+3
  const int slot = threadIdx.x >> 5;   // 0..7
  const int v    = blockIdx.x*8 + slot;
  const bool valid = v < n;

  int beg = 0, end = 0;
  float dv = 0.f;
  float4 selfh = make_float4(0.f,0.f,0.f,0.f);
  if (valid){
    beg = rowptr[v]; end = rowptr[v+1];
    dv  = dinv[v];
    selfh = h4[(size_t)v*32 + c];
  }

  float4 acc = make_float4(0.f,0.f,0.f,0.f);
  int j = beg;
  for (; j+1 < end; j += 2){
    int2 p0 = colpk[j], p1 = colpk[j+1];
    float4 h0 = h4[(size_t)p0.x*32 + c];
    float4 h1 = h4[(size_t)p1.x*32 + c];
    float w0 = __int_as_float(p0.y), w1 = __int_as_float(p1.y);
    acc.x = fmaf(w0,h0.x,acc.x); acc.y = fmaf(w0,h0.y,acc.y);
    acc.z = fmaf(w0,h0.z,acc.z); acc.w = fmaf(w0,h0.w,acc.w);
    acc.x = fmaf(w1,h1.x,acc.x); acc.y = fmaf(w1,h1.y,acc.y);
    acc.z = fmaf(w1,h1.z,acc.z); acc.w = fmaf(w1,h1.w,acc.w);
  }
  if (j < end){
    int2 p = colpk[j];
    float4 hv = h4[(size_t)p.x*32 + c];
    float w = __int_as_float(p.y);
    acc.x = fmaf(w,hv.x,acc.x); acc.y = fmaf(w,hv.y,acc.y);
    acc.z = fmaf(w,hv.z,acc.z); acc.w = fmaf(w,hv.w,acc.w);
  }

  acc.x = dv*(acc.x + dv*selfh.x);
  acc.y = dv*(acc.y + dv*selfh.y);
  acc.z = dv*(acc.z + dv*selfh.z);
  acc.w = dv*(acc.w + dv*selfh.w);

  if (valid){
    float4* op = (float4*)(out + (size_t)v*512 + colOff);
    op[c] = acc;
    int f = c*4;
    atomicAdd(&ssum[f+0], acc.x);           atomicAdd(&ssum[f+1], acc.y);
    atomicAdd(&ssum[f+2], acc.z);           atomicAdd(&ssum[f+3], acc.w);
    atomicAdd(&ssum[128+f+0], acc.x*acc.x); atomicAdd(&ssum[128+f+1], acc.y*acc.y);
    atomicAdd(&ssum[128+f+2], acc.z*acc.z); atomicAdd(&ssum[128+f+3], acc.w*acc.w);
  }
  __syncthreads();
  atomicAdd(&stats[threadIdx.x], ssum[threadIdx.x]);
}

// scale/shift precompute: o = val*scale[f] + shift[f], then ReLU
__global__ void k_bnprep(const float* __restrict__ stats,
                         const float* __restrict__ gamma, const float* __restrict__ beta,
                         float* __restrict__ ss, int n){
  int f = threadIdx.x;
  if (f < 128){
    float invn = 1.0f / (float)n;
    float mu  = stats[f] * invn;
    float var = stats[128 + f] * invn - mu*mu;
    float rs  = rsqrtf(var + EPS_BN);
    float sc  = gamma[f] * rs;
    ss[f]       = sc;
    ss[128 + f] = beta[f] - mu * sc;
  }
}

__global__ void k_bnrelu(float* __restrict__ out, int colOff,
                         const float* __restrict__ ss, int n){
  int i = blockIdx.x*256 + threadIdx.x;
  if (i >= n*32) return;
  int v = i >> 5, c = i & 31;
  int f = c*4;
  float4* p = (float4*)(out + (size_t)v*512 + colOff);
  float4 val = p[c];
  val.x = fmaxf(fmaf(val.x, ss[f+0], ss[128+f+0]), 0.f);
  val.y = fmaxf(fmaf(val.y, ss[f+1], ss[128+f+1]), 0.f);
  val.z = fmaxf(fmaf(val.z, ss[f+2], ss[128+f+2]), 0.f);
  val.w = fmaxf(fmaf(val.w, ss[f+3], ss[128+f+3]), 0.f);
  p[c] = val;
}

extern "C" void kernel_launch(void* const* d_in, const int* in_sizes, int n_in,
                              void* d_out, int out_size, void* d_ws, size_t ws_size,
                              hipStream_t stream){
  const float* x      = (const float*)d_in[0];
  const int*   ei     = (const int*)d_in[1];
  const float* Ws     = (const float*)d_in[2];
  // d_in[3] = bs: cancels exactly in BatchNorm
  const float* gammas = (const float*)d_in[4];
  const float* betas  = (const float*)d_in[5];
  const int N = in_sizes[0] / 128;
  const int E = in_sizes[1] / 2;
  float* out = (float*)d_out;

  char* w = (char*)d_ws;
  auto alloc = [&](size_t bytes)->char*{
    char* p = w; w += (bytes + 255) & ~(size_t)255; return p;
  };
  int*   cnt    = (int*)  alloc((size_t)N*4);
  int*   cur    = (int*)  alloc((size_t)N*4);
  int*   rowptr = (int*)  alloc((size_t)(N+1)*4);
  int*   blksum = (int*)  alloc(64*4);
  int2*  colpk  = (int2*) alloc((size_t)E*8);
  float* dinv   = (float*)alloc((size_t)N*4);
  float* stats  = (float*)alloc(256*4);
  float* ss     = (float*)alloc(256*4);
  float* h      = (float*)alloc((size_t)N*128*4);

  const int* srcArr = ei;
  const int* dstArr = ei + E;

  const int nbN = (N + 255)/256;
  const int nbE = (E + 255)/256;
  const int nscan = (N + 1023)/1024;

  k_zero_i32<<<nbN,256,0,stream>>>(cnt, N);
  k_zero_i32<<<nbN,256,0,stream>>>(cur, N);
  k_count<<<nbE,256,0,stream>>>(dstArr, cnt, E);
  k_dinv<<<nbN,256,0,stream>>>(cnt, dinv, N);
  k_scan1<<<nscan,256,0,stream>>>(cnt, rowptr, blksum, N);
  k_scan2<<<1,64,0,stream>>>(blksum, nscan);
  k_scan3<<<nbN,256,0,stream>>>(rowptr, blksum, N, E);
  k_fill<<<nbE,256,0,stream>>>(srcArr, dstArr, dinv, rowptr, cur, colpk, E);
  k_copyx<<<(N*32 + 255)/256,256,0,stream>>>((const float4*)x, out, N*32);

  for (int l=0; l<3; l++){
    k_gemm<<<(N + 63)/64,256,0,stream>>>(out + l*128, Ws + (size_t)l*128*128, h, N);
    k_zero_f32<<<1,256,0,stream>>>(stats, 256);
    k_agg<<<(N + 7)/8,256,0,stream>>>((const float4*)h, rowptr, colpk, dinv, out,
                                      (l+1)*128, stats, N);
    k_bnprep<<<1,128,0,stream>>>(stats, gammas + l*128, betas + l*128, ss, N);
    k_bnrelu<<<((N*32) + 255)/256,256,0,stream>>>(out, (l+1)*128, ss, N);
  }
}

// Round 3
// 555.265 us; speedup vs baseline: 1.5570x; 1.5570x over previous
//
#include <hip/hip_runtime.h>

// GCN: 3 layers of {h = o@W; agg = Dinv(A+I)Dinv h; BN+ReLU}, JK concat.
// N=50000, E=800000, D=128, L=3. All fp32.
// CSR rows padded to multiple of 8 with (src=0, w=0) dummies -> tail-free unroll-8 gather.

#define EPS_BN 1e-5f
#define NPB 8          // nodes per k_agg block
#define NB_STATS 128   // partial-stats blocks

__global__ void k_zero_i32(int* __restrict__ p, int n){
  int i = blockIdx.x*256 + threadIdx.x;
  if (i < n) p[i] = 0;
}

__global__ void k_count(const int* __restrict__ dst, int* __restrict__ cnt, int E){
  int i = blockIdx.x*256 + threadIdx.x;
  if (i < E) atomicAdd(&cnt[dst[i]], 1);
}

// exclusive scan of PADDED counts ((cnt+7)&~7) -> rowptr; also emits dinv from raw cnt
__global__ void k_scan1(const int* __restrict__ cnt, int* __restrict__ out,
                        int* __restrict__ blksum, float* __restrict__ dinv, int n){
  __shared__ int sh[256];
  int t = threadIdx.x;
  int base = blockIdx.x*1024 + t*4;
  int v[4];
  #pragma unroll
  for (int j=0;j<4;j++){
    int raw = (base+j < n) ? cnt[base+j] : 0;
    if (base+j < n) dinv[base+j] = rsqrtf((float)raw + 1.0f);  // +1 self loop
    v[j] = (base+j < n) ? ((raw + 7) & ~7) : 0;                // padded count
  }
  int tsum = v[0]+v[1]+v[2]+v[3];
  sh[t] = tsum;
  __syncthreads();
  #pragma unroll
  for (int off=1; off<256; off<<=1){
    int x = (t>=off) ? sh[t-off] : 0;
    __syncthreads();
    sh[t] += x;
    __syncthreads();
  }
  if (t==255) blksum[blockIdx.x] = sh[255];
  int run = sh[t] - tsum;
  #pragma unroll
  for (int j=0;j<4;j++){ if (base+j < n) out[base+j] = run; run += v[j]; }
}

__global__ void k_scan2(int* __restrict__ blksum, int nb, int* __restrict__ total){
  if (threadIdx.x == 0){
    int run = 0;
    for (int i=0;i<nb;i++){ int v = blksum[i]; blksum[i] = run; run += v; }
    *total = run;
  }
}

__global__ void k_scan3(int* __restrict__ out, int* __restrict__ rowcur,
                        const int* __restrict__ blksum, const int* __restrict__ total,
                        int n){
  int i = blockIdx.x*256 + threadIdx.x;
  if (i < n){
    int r = out[i] + blksum[i >> 10];
    out[i] = r;
    rowcur[i] = r;
  }
  if (i == 0) out[n] = *total;
}

__global__ void k_fill(const int* __restrict__ src, const int* __restrict__ dst,
                       const float* __restrict__ dinv,
                       int* __restrict__ rowcur, int2* __restrict__ colpk, int E){
  int e = blockIdx.x*256 + threadIdx.x;
  if (e < E){
    int d = dst[e];
    int pos = atomicAdd(&rowcur[d], 1);
    int s = src[e];
    colpk[pos] = make_int2(s, __float_as_int(dinv[s]));
  }
}

__global__ void k_copyx(const float4* __restrict__ x, float* __restrict__ out, int n4){
  int i = blockIdx.x*256 + threadIdx.x;
  if (i < n4){
    int v = i >> 5, f4 = i & 31;
    ((float4*)(out + (size_t)v*512))[f4] = x[i];
  }
}

// H[N,128] = A[N,128](lda) @ W[128,128].  W fully in LDS (64KB).
// Block: 64 rows x 128 cols, 256 threads, each thread 4 rows x 8 cols.
__launch_bounds__(256)
__global__ void k_gemm(const float* __restrict__ A, int lda, const float* __restrict__ W,
                       float* __restrict__ H, int n){
  __shared__ float4 Wl[4096];          // 64KB
  const float4* W4 = (const float4*)W;
  #pragma unroll
  for (int j=0;j<16;j++) Wl[threadIdx.x + j*256] = W4[threadIdx.x + j*256];
  __syncthreads();

  const int t  = threadIdx.x;
  const int cx = t & 15;
  const int ry = t >> 4;
  const int r0 = blockIdx.x*64 + ry*4;

  float acc[4][8];
  #pragma unroll
  for (int a=0;a<4;a++)
    #pragma unroll
    for (int b=0;b<8;b++) acc[a][b] = 0.f;

  const float4* Arow[4];
  #pragma unroll
  for (int rr=0;rr<4;rr++){
    int r = r0 + rr; if (r > n-1) r = n-1;
    Arow[rr] = (const float4*)(A + (size_t)r*lda);
  }
  const int cb = cx*2;

  for (int k4=0;k4<32;k4++){
    float4 a0 = Arow[0][k4], a1 = Arow[1][k4], a2 = Arow[2][k4], a3 = Arow[3][k4];
    #pragma unroll
    for (int kk=0;kk<4;kk++){
      int k = k4*4 + kk;
      float4 w0 = Wl[k*32 + cb];
      float4 w1 = Wl[k*32 + cb + 1];
      float av0 = ((const float*)&a0)[kk];
      float av1 = ((const float*)&a1)[kk];
      float av2 = ((const float*)&a2)[kk];
      float av3 = ((const float*)&a3)[kk];
      float wv[8] = {w0.x,w0.y,w0.z,w0.w,w1.x,w1.y,w1.z,w1.w};
      #pragma unroll
      for (int c=0;c<8;c++){
        acc[0][c] = fmaf(av0, wv[c], acc[0][c]);
        acc[1][c] = fmaf(av1, wv[c], acc[1][c]);
        acc[2][c] = fmaf(av2, wv[c], acc[2][c]);
        acc[3][c] = fmaf(av3, wv[c], acc[3][c]);
      }
    }
  }
  #pragma unroll
  for (int rr=0;rr<4;rr++){
    int r = r0 + rr;
    if (r < n){
      float4* Hp = (float4*)(H + (size_t)r*128 + cx*8);
      Hp[0] = make_float4(acc[rr][0],acc[rr][1],acc[rr][2],acc[rr][3]);
      Hp[1] = make_float4(acc[rr][4],acc[rr][5],acc[rr][6],acc[rr][7]);
    }
  }
}

// Pull-based aggregation. 128 threads (f = feature), NPB nodes per block serially.
// Rows padded to x8 -> exact unroll-8, 8 gathers in flight, no tail, no atomics.
__launch_bounds__(128)
__global__ void k_agg(const float* __restrict__ h, const int* __restrict__ rowptr,
                      const int2* __restrict__ colpk, const float* __restrict__ dinv,
                      float* __restrict__ out, int colOff, int n){
  const int f = threadIdx.x;
  const int v0 = blockIdx.x*NPB;
  #pragma unroll 1
  for (int vi=0; vi<NPB; vi++){
    int v = v0 + vi;
    if (v >= n) return;
    int j = rowptr[v], end = rowptr[v+1];
    float acc = 0.f;
    #pragma unroll 1
    for (; j < end; j += 8){
      int2 p0=colpk[j],   p1=colpk[j+1], p2=colpk[j+2], p3=colpk[j+3];
      int2 p4=colpk[j+4], p5=colpk[j+5], p6=colpk[j+6], p7=colpk[j+7];
      float h0=h[(size_t)p0.x*128+f], h1=h[(size_t)p1.x*128+f];
      float h2=h[(size_t)p2.x*128+f], h3=h[(size_t)p3.x*128+f];
      float h4=h[(size_t)p4.x*128+f], h5=h[(size_t)p5.x*128+f];
      float h6=h[(size_t)p6.x*128+f], h7=h[(size_t)p7.x*128+f];
      acc = fmaf(__int_as_float(p0.y), h0, acc);
      acc = fmaf(__int_as_float(p1.y), h1, acc);
      acc = fmaf(__int_as_float(p2.y), h2, acc);
      acc = fmaf(__int_as_float(p3.y), h3, acc);
      acc = fmaf(__int_as_float(p4.y), h4, acc);
      acc = fmaf(__int_as_float(p5.y), h5, acc);
      acc = fmaf(__int_as_float(p6.y), h6, acc);
      acc = fmaf(__int_as_float(p7.y), h7, acc);
    }
    float dv = dinv[v];
    acc = dv * (acc + dv * h[(size_t)v*128 + f]);   // self loop
    out[(size_t)v*512 + colOff + f] = acc;
  }
}

// streaming per-feature partial sums (no atomics)
__launch_bounds__(128)
__global__ void k_stats(const float* __restrict__ out, int colOff,
                        float* __restrict__ partial, int n){
  const int f = threadIdx.x;
  int per = (n + NB_STATS - 1)/NB_STATS;
  int v0 = blockIdx.x*per;
  int v1 = min(n, v0 + per);
  float s = 0.f, s2 = 0.f;
  #pragma unroll 4
  for (int v=v0; v<v1; v++){
    float a = out[(size_t)v*512 + colOff + f];
    s += a; s2 = fmaf(a, a, s2);
  }
  partial[blockIdx.x*256 + f]       = s;
  partial[blockIdx.x*256 + 128 + f] = s2;
}

__global__ void k_bnprep(const float* __restrict__ partial,
                         const float* __restrict__ gamma, const float* __restrict__ beta,
                         float* __restrict__ ss, int n){
  int f = threadIdx.x;
  if (f < 128){
    float s = 0.f, s2 = 0.f;
    #pragma unroll 4
    for (int i=0;i<NB_STATS;i++){
      s  += partial[i*256 + f];
      s2 += partial[i*256 + 128 + f];
    }
    float invn = 1.0f / (float)n;
    float mu  = s * invn;
    float var = s2 * invn - mu*mu;
    float rs  = rsqrtf(var + EPS_BN);
    float sc  = gamma[f] * rs;
    ss[f]       = sc;
    ss[128 + f] = beta[f] - mu * sc;
  }
}

__global__ void k_bnrelu(float* __restrict__ out, int colOff,
                         const float* __restrict__ ss, int n){
  int i = blockIdx.x*256 + threadIdx.x;
  if (i >= n*32) return;
  int v = i >> 5, c = i & 31;
  int f = c*4;
  float4* p = (float4*)(out + (size_t)v*512 + colOff);
  float4 val = p[c];
  val.x = fmaxf(fmaf(val.x, ss[f+0], ss[128+f+0]), 0.f);
  val.y = fmaxf(fmaf(val.y, ss[f+1], ss[128+f+1]), 0.f);
  val.z = fmaxf(fmaf(val.z, ss[f+2], ss[128+f+2]), 0.f);
  val.w = fmaxf(fmaf(val.w, ss[f+3], ss[128+f+3]), 0.f);
  p[c] = val;
}

extern "C" void kernel_launch(void* const* d_in, const int* in_sizes, int n_in,
                              void* d_out, int out_size, void* d_ws, size_t ws_size,
                              hipStream_t stream){
  const float* x      = (const float*)d_in[0];
  const int*   ei     = (const int*)d_in[1];
  const float* Ws     = (const float*)d_in[2];
  // d_in[3] = bs: cancels exactly in BatchNorm
  const float* gammas = (const float*)d_in[4];
  const float* betas  = (const float*)d_in[5];
  const int N = in_sizes[0] / 128;
  const int E = in_sizes[1] / 2;
  float* out = (float*)d_out;

  const int EPADCAP = E + 7*N + 8;   // padded-CSR capacity

  char* w = (char*)d_ws;
  auto alloc = [&](size_t bytes)->char*{
    char* p = w; w += (bytes + 255) & ~(size_t)255; return p;
  };
  int*   cnt    = (int*)  alloc((size_t)N*4);
  int*   rowptr = (int*)  alloc((size_t)(N+1)*4);
  int*   rowcur = (int*)  alloc((size_t)N*4);
  int*   blksum = (int*)  alloc(64*4);
  int*   total  = (int*)  alloc(64);
  int2*  colpk  = (int2*) alloc((size_t)EPADCAP*8);
  float* dinv   = (float*)alloc((size_t)N*4);
  float* partial= (float*)alloc((size_t)NB_STATS*256*4);
  float* ss     = (float*)alloc(256*4);
  float* h      = (float*)alloc((size_t)N*128*4);

  const int* srcArr = ei;
  const int* dstArr = ei + E;

  const int nbN = (N + 255)/256;
  const int nbE = (E + 255)/256;
  const int nscan = (N + 1023)/1024;
  const int nPadInts = EPADCAP*2;

  k_zero_i32<<<nbN,256,0,stream>>>(cnt, N);
  k_zero_i32<<<(nPadInts + 255)/256,256,0,stream>>>((int*)colpk, nPadInts);
  k_count<<<nbE,256,0,stream>>>(dstArr, cnt, E);
  k_scan1<<<nscan,256,0,stream>>>(cnt, rowptr, blksum, dinv, N);
  k_scan2<<<1,64,0,stream>>>(blksum, nscan, total);
  k_scan3<<<nbN,256,0,stream>>>(rowptr, rowcur, blksum, total, N);
  k_fill<<<nbE,256,0,stream>>>(srcArr, dstArr, dinv, rowcur, colpk, E);
  k_copyx<<<(N*32 + 255)/256,256,0,stream>>>((const float4*)x, out, N*32);

  for (int l=0; l<3; l++){
    const float* A = (l == 0) ? x : (out + l*128);
    int lda = (l == 0) ? 128 : 512;
    k_gemm<<<(N + 63)/64,256,0,stream>>>(A, lda, Ws + (size_t)l*128*128, h, N);
    k_agg<<<(N + NPB-1)/NPB,128,0,stream>>>(h, rowptr, colpk, dinv, out,
                                            (l+1)*128, N);
    k_stats<<<NB_STATS,128,0,stream>>>(out, (l+1)*128, partial, N);
    k_bnprep<<<1,128,0,stream>>>(partial, gammas + l*128, betas + l*128, ss, N);
    k_bnrelu<<<((N*32) + 255)/256,256,0,stream>>>(out, (l+1)*128, ss, N);
  }
}

// Round 4
// 441.854 us; speedup vs baseline: 1.9567x; 1.2567x over previous
//
#include <hip/hip_runtime.h>

// GCN: 3 layers of {h = o@W; agg = Dinv(A+I)Dinv h; BN+ReLU}, JK concat.
// N=50000, E=800000, D=128, L=3.
// h stored as packed bf16x2 (row = 256B); k_agg: 1 wave per node-row,
// 1 dword gather per edge, wave-uniform scalar index loads.
// CSR rows padded to multiple of 8 -> tail-free unroll-8.

#define EPS_BN 1e-5f
#define NPW 4          // nodes per wave in k_agg
#define NB_STATS 256   // partial-stats blocks

__device__ __forceinline__ unsigned bf16rne(float f){
  unsigned x = __float_as_uint(f);
  return (x + 0x7fffu + ((x >> 16) & 1u)) >> 16;   // round-to-nearest-even
}
__device__ __forceinline__ float bflo(unsigned q){ return __uint_as_float(q << 16); }
__device__ __forceinline__ float bfhi(unsigned q){ return __uint_as_float(q & 0xffff0000u); }

__global__ void k_zero_i32(int* __restrict__ p, int n){
  int i = blockIdx.x*256 + threadIdx.x;
  if (i < n) p[i] = 0;
}

__global__ void k_count(const int* __restrict__ dst, int* __restrict__ cnt, int E){
  int i = blockIdx.x*256 + threadIdx.x;
  if (i < E) atomicAdd(&cnt[dst[i]], 1);
}

// exclusive scan of PADDED counts ((cnt+7)&~7) -> rowptr; also emits dinv from raw cnt
__global__ void k_scan1(const int* __restrict__ cnt, int* __restrict__ out,
                        int* __restrict__ blksum, float* __restrict__ dinv, int n){
  __shared__ int sh[256];
  int t = threadIdx.x;
  int base = blockIdx.x*1024 + t*4;
  int v[4];
  #pragma unroll
  for (int j=0;j<4;j++){
    int raw = (base+j < n) ? cnt[base+j] : 0;
    if (base+j < n) dinv[base+j] = rsqrtf((float)raw + 1.0f);  // +1 self loop
    v[j] = (base+j < n) ? ((raw + 7) & ~7) : 0;                // padded count
  }
  int tsum = v[0]+v[1]+v[2]+v[3];
  sh[t] = tsum;
  __syncthreads();
  #pragma unroll
  for (int off=1; off<256; off<<=1){
    int x = (t>=off) ? sh[t-off] : 0;
    __syncthreads();
    sh[t] += x;
    __syncthreads();
  }
  if (t==255) blksum[blockIdx.x] = sh[255];
  int run = sh[t] - tsum;
  #pragma unroll
  for (int j=0;j<4;j++){ if (base+j < n) out[base+j] = run; run += v[j]; }
}

__global__ void k_scan2(int* __restrict__ blksum, int nb, int* __restrict__ total){
  if (threadIdx.x == 0){
    int run = 0;
    for (int i=0;i<nb;i++){ int v = blksum[i]; blksum[i] = run; run += v; }
    *total = run;
  }
}

__global__ void k_scan3(int* __restrict__ out, int* __restrict__ rowcur,
                        const int* __restrict__ blksum, const int* __restrict__ total,
                        int n){
  int i = blockIdx.x*256 + threadIdx.x;
  if (i < n){
    int r = out[i] + blksum[i >> 10];
    out[i] = r;
    rowcur[i] = r;
  }
  if (i == 0) out[n] = *total;
}

__global__ void k_fill(const int* __restrict__ src, const int* __restrict__ dst,
                       const float* __restrict__ dinv,
                       int* __restrict__ rowcur, int2* __restrict__ colpk, int E){
  int e = blockIdx.x*256 + threadIdx.x;
  if (e < E){
    int d = dst[e];
    int pos = atomicAdd(&rowcur[d], 1);
    int s = src[e];
    colpk[pos] = make_int2(s, __float_as_int(dinv[s]));
  }
}

__global__ void k_copyx(const float4* __restrict__ x, float* __restrict__ out, int n4){
  int i = blockIdx.x*256 + threadIdx.x;
  if (i < n4){
    int v = i >> 5, f4 = i & 31;
    ((float4*)(out + (size_t)v*512))[f4] = x[i];
  }
}

// H2[N][64] (packed bf16x2) = A[N,128](lda) @ W[128,128].  W fully in LDS (64KB).
// Block: 64 rows x 128 cols, 256 threads, each thread 4 rows x 8 cols.
__launch_bounds__(256)
__global__ void k_gemm(const float* __restrict__ A, int lda, const float* __restrict__ W,
                       unsigned* __restrict__ H2, int n){
  __shared__ float4 Wl[4096];          // 64KB
  const float4* W4 = (const float4*)W;
  #pragma unroll
  for (int j=0;j<16;j++) Wl[threadIdx.x + j*256] = W4[threadIdx.x + j*256];
  __syncthreads();

  const int t  = threadIdx.x;
  const int cx = t & 15;
  const int ry = t >> 4;
  const int r0 = blockIdx.x*64 + ry*4;

  float acc[4][8];
  #pragma unroll
  for (int a=0;a<4;a++)
    #pragma unroll
    for (int b=0;b<8;b++) acc[a][b] = 0.f;

  const float4* Arow[4];
  #pragma unroll
  for (int rr=0;rr<4;rr++){
    int r = r0 + rr; if (r > n-1) r = n-1;
    Arow[rr] = (const float4*)(A + (size_t)r*lda);
  }
  const int cb = cx*2;

  for (int k4=0;k4<32;k4++){
    float4 a0 = Arow[0][k4], a1 = Arow[1][k4], a2 = Arow[2][k4], a3 = Arow[3][k4];
    #pragma unroll
    for (int kk=0;kk<4;kk++){
      int k = k4*4 + kk;
      float4 w0 = Wl[k*32 + cb];
      float4 w1 = Wl[k*32 + cb + 1];
      float av0 = ((const float*)&a0)[kk];
      float av1 = ((const float*)&a1)[kk];
      float av2 = ((const float*)&a2)[kk];
      float av3 = ((const float*)&a3)[kk];
      float wv[8] = {w0.x,w0.y,w0.z,w0.w,w1.x,w1.y,w1.z,w1.w};
      #pragma unroll
      for (int c=0;c<8;c++){
        acc[0][c] = fmaf(av0, wv[c], acc[0][c]);
        acc[1][c] = fmaf(av1, wv[c], acc[1][c]);
        acc[2][c] = fmaf(av2, wv[c], acc[2][c]);
        acc[3][c] = fmaf(av3, wv[c], acc[3][c]);
      }
    }
  }
  #pragma unroll
  for (int rr=0;rr<4;rr++){
    int r = r0 + rr;
    if (r < n){
      uint4 pk;
      pk.x = bf16rne(acc[rr][0]) | (bf16rne(acc[rr][1]) << 16);
      pk.y = bf16rne(acc[rr][2]) | (bf16rne(acc[rr][3]) << 16);
      pk.z = bf16rne(acc[rr][4]) | (bf16rne(acc[rr][5]) << 16);
      pk.w = bf16rne(acc[rr][6]) | (bf16rne(acc[rr][7]) << 16);
      *(uint4*)(H2 + (size_t)r*64 + cx*4) = pk;
    }
  }
}

// Pull-based aggregation. 1 wave per node-row: lane l covers features 2l,2l+1.
// Per edge: 1 scalar int2 index load + 1 dword gather (256B/wave).
// Rows padded to x8 -> exact unroll-8, 8 gathers in flight, no tail, no atomics.
__launch_bounds__(256)
__global__ void k_agg(const unsigned* __restrict__ h2, const int* __restrict__ rowptr,
                      const int2* __restrict__ colpk, const float* __restrict__ dinv,
                      float* __restrict__ out, int colOff, int n){
  const int lane = threadIdx.x & 63;
  const int wv   = __builtin_amdgcn_readfirstlane(threadIdx.x >> 6);
  const int v0   = (blockIdx.x*4 + wv) * NPW;
  #pragma unroll 1
  for (int vi=0; vi<NPW; vi++){
    int v = v0 + vi;
    if (v >= n) return;
    int j = rowptr[v], end = rowptr[v+1];
    float a0 = 0.f, a1 = 0.f;
    #pragma unroll 1
    for (; j < end; j += 8){
      int2 p0=colpk[j],   p1=colpk[j+1], p2=colpk[j+2], p3=colpk[j+3];
      int2 p4=colpk[j+4], p5=colpk[j+5], p6=colpk[j+6], p7=colpk[j+7];
      unsigned q0=h2[(size_t)p0.x*64+lane], q1=h2[(size_t)p1.x*64+lane];
      unsigned q2=h2[(size_t)p2.x*64+lane], q3=h2[(size_t)p3.x*64+lane];
      unsigned q4=h2[(size_t)p4.x*64+lane], q5=h2[(size_t)p5.x*64+lane];
      unsigned q6=h2[(size_t)p6.x*64+lane], q7=h2[(size_t)p7.x*64+lane];
      float w0=__int_as_float(p0.y), w1=__int_as_float(p1.y);
      float w2=__int_as_float(p2.y), w3=__int_as_float(p3.y);
      float w4=__int_as_float(p4.y), w5=__int_as_float(p5.y);
      float w6=__int_as_float(p6.y), w7=__int_as_float(p7.y);
      a0 = fmaf(w0, bflo(q0), a0);  a1 = fmaf(w0, bfhi(q0), a1);
      a0 = fmaf(w1, bflo(q1), a0);  a1 = fmaf(w1, bfhi(q1), a1);
      a0 = fmaf(w2, bflo(q2), a0);  a1 = fmaf(w2, bfhi(q2), a1);
      a0 = fmaf(w3, bflo(q3), a0);  a1 = fmaf(w3, bfhi(q3), a1);
      a0 = fmaf(w4, bflo(q4), a0);  a1 = fmaf(w4, bfhi(q4), a1);
      a0 = fmaf(w5, bflo(q5), a0);  a1 = fmaf(w5, bfhi(q5), a1);
      a0 = fmaf(w6, bflo(q6), a0);  a1 = fmaf(w6, bfhi(q6), a1);
      a0 = fmaf(w7, bflo(q7), a0);  a1 = fmaf(w7, bfhi(q7), a1);
    }
    float dv = dinv[v];
    unsigned qs = h2[(size_t)v*64 + lane];
    a0 = dv*(a0 + dv*bflo(qs));
    a1 = dv*(a1 + dv*bfhi(qs));
    *(float2*)(out + (size_t)v*512 + colOff + lane*2) = make_float2(a0, a1);
  }
}

// streaming per-feature partial sums (no atomics)
__launch_bounds__(128)
__global__ void k_stats(const float* __restrict__ out, int colOff,
                        float* __restrict__ partial, int n){
  const int f = threadIdx.x;
  int per = (n + NB_STATS - 1)/NB_STATS;
  int v0 = blockIdx.x*per;
  int v1 = min(n, v0 + per);
  float s = 0.f, s2 = 0.f;
  #pragma unroll 4
  for (int v=v0; v<v1; v++){
    float a = out[(size_t)v*512 + colOff + f];
    s += a; s2 = fmaf(a, a, s2);
  }
  partial[blockIdx.x*256 + f]       = s;
  partial[blockIdx.x*256 + 128 + f] = s2;
}

__global__ void k_bnprep(const float* __restrict__ partial,
                         const float* __restrict__ gamma, const float* __restrict__ beta,
                         float* __restrict__ ss, int n){
  int f = threadIdx.x;
  if (f < 128){
    float s = 0.f, s2 = 0.f;
    #pragma unroll 4
    for (int i=0;i<NB_STATS;i++){
      s  += partial[i*256 + f];
      s2 += partial[i*256 + 128 + f];
    }
    float invn = 1.0f / (float)n;
    float mu  = s * invn;
    float var = s2 * invn - mu*mu;
    float rs  = rsqrtf(var + EPS_BN);
    float sc  = gamma[f] * rs;
    ss[f]       = sc;
    ss[128 + f] = beta[f] - mu * sc;
  }
}

__global__ void k_bnrelu(float* __restrict__ out, int colOff,
                         const float* __restrict__ ss, int n){
  int i = blockIdx.x*256 + threadIdx.x;
  if (i >= n*32) return;
  int v = i >> 5, c = i & 31;
  int f = c*4;
  float4* p = (float4*)(out + (size_t)v*512 + colOff);
  float4 val = p[c];
  val.x = fmaxf(fmaf(val.x, ss[f+0], ss[128+f+0]), 0.f);
  val.y = fmaxf(fmaf(val.y, ss[f+1], ss[128+f+1]), 0.f);
  val.z = fmaxf(fmaf(val.z, ss[f+2], ss[128+f+2]), 0.f);
  val.w = fmaxf(fmaf(val.w, ss[f+3], ss[128+f+3]), 0.f);
  p[c] = val;
}

extern "C" void kernel_launch(void* const* d_in, const int* in_sizes, int n_in,
                              void* d_out, int out_size, void* d_ws, size_t ws_size,
                              hipStream_t stream){
  const float* x      = (const float*)d_in[0];
  const int*   ei     = (const int*)d_in[1];
  const float* Ws     = (const float*)d_in[2];
  // d_in[3] = bs: cancels exactly in BatchNorm
  const float* gammas = (const float*)d_in[4];
  const float* betas  = (const float*)d_in[5];
  const int N = in_sizes[0] / 128;
  const int E = in_sizes[1] / 2;
  float* out = (float*)d_out;

  const int EPADCAP = E + 7*N + 8;   // padded-CSR capacity

  char* w = (char*)d_ws;
  auto alloc = [&](size_t bytes)->char*{
    char* p = w; w += (bytes + 255) & ~(size_t)255; return p;
  };
  int*      cnt    = (int*)     alloc((size_t)N*4);
  int*      rowptr = (int*)     alloc((size_t)(N+1)*4);
  int*      rowcur = (int*)     alloc((size_t)N*4);
  int*      blksum = (int*)     alloc(64*4);
  int*      total  = (int*)     alloc(64);
  int2*     colpk  = (int2*)    alloc((size_t)EPADCAP*8);
  float*    dinv   = (float*)   alloc((size_t)N*4);
  float*    partial= (float*)   alloc((size_t)NB_STATS*256*4);
  float*    ss     = (float*)   alloc(256*4);
  unsigned* h2     = (unsigned*)alloc((size_t)N*64*4);

  const int* srcArr = ei;
  const int* dstArr = ei + E;

  const int nbN = (N + 255)/256;
  const int nbE = (E + 255)/256;
  const int nscan = (N + 1023)/1024;
  const int nPadInts = EPADCAP*2;

  k_zero_i32<<<nbN,256,0,stream>>>(cnt, N);
  k_zero_i32<<<(nPadInts + 255)/256,256,0,stream>>>((int*)colpk, nPadInts);
  k_count<<<nbE,256,0,stream>>>(dstArr, cnt, E);
  k_scan1<<<nscan,256,0,stream>>>(cnt, rowptr, blksum, dinv, N);
  k_scan2<<<1,64,0,stream>>>(blksum, nscan, total);
  k_scan3<<<nbN,256,0,stream>>>(rowptr, rowcur, blksum, total, N);
  k_fill<<<nbE,256,0,stream>>>(srcArr, dstArr, dinv, rowcur, colpk, E);
  k_copyx<<<(N*32 + 255)/256,256,0,stream>>>((const float4*)x, out, N*32);

  for (int l=0; l<3; l++){
    const float* A = (l == 0) ? x : (out + l*128);
    int lda = (l == 0) ? 128 : 512;
    k_gemm<<<(N + 63)/64,256,0,stream>>>(A, lda, Ws + (size_t)l*128*128, h2, N);
    k_agg<<<(N + 4*NPW-1)/(4*NPW),256,0,stream>>>(h2, rowptr, colpk, dinv, out,
                                                  (l+1)*128, N);
    k_stats<<<NB_STATS,128,0,stream>>>(out, (l+1)*128, partial, N);
    k_bnprep<<<1,128,0,stream>>>(partial, gammas + l*128, betas + l*128, ss, N);
    k_bnrelu<<<((N*32) + 255)/256,256,0,stream>>>(out, (l+1)*128, ss, N);
  }
}

// Round 5
// 298.270 us; speedup vs baseline: 2.8986x; 1.4814x over previous
//
#include <hip/hip_runtime.h>

// GCN: 3 layers of {h = o@W (MFMA bf16); agg = Dinv(A+I)Dinv h + fused BN stats; BN+ReLU}, JK concat.
// N=50000, E=800000, D=128, L=3.
// h stored as packed bf16x2 (row = 256B); k_agg: 1 wave per node-row,
// 1 dword gather per edge; CSR rows padded to x8 -> tail-free unroll-8.

#define EPS_BN 1e-5f
#define NPW 4          // nodes per wave in k_agg

typedef short short8v __attribute__((ext_vector_type(8)));
typedef float float4v __attribute__((ext_vector_type(4)));

__device__ __forceinline__ unsigned bf16rne(float f){
  unsigned x = __float_as_uint(f);
  return (x + 0x7fffu + ((x >> 16) & 1u)) >> 16;   // round-to-nearest-even
}
__device__ __forceinline__ float bflo(unsigned q){ return __uint_as_float(q << 16); }
__device__ __forceinline__ float bfhi(unsigned q){ return __uint_as_float(q & 0xffff0000u); }

__global__ void k_zero_i32(int* __restrict__ p, int n){
  int i = blockIdx.x*256 + threadIdx.x;
  if (i < n) p[i] = 0;
}

__global__ void k_count(const int* __restrict__ dst, int* __restrict__ cnt, int E){
  int i = blockIdx.x*256 + threadIdx.x;
  if (i < E) atomicAdd(&cnt[dst[i]], 1);
}

// exclusive scan of PADDED counts ((cnt+7)&~7) -> rowptr; also emits dinv from raw cnt
__global__ void k_scan1(const int* __restrict__ cnt, int* __restrict__ out,
                        int* __restrict__ blksum, float* __restrict__ dinv, int n){
  __shared__ int sh[256];
  int t = threadIdx.x;
  int base = blockIdx.x*1024 + t*4;
  int v[4];
  #pragma unroll
  for (int j=0;j<4;j++){
    int raw = (base+j < n) ? cnt[base+j] : 0;
    if (base+j < n) dinv[base+j] = rsqrtf((float)raw + 1.0f);  // +1 self loop
    v[j] = (base+j < n) ? ((raw + 7) & ~7) : 0;                // padded count
  }
  int tsum = v[0]+v[1]+v[2]+v[3];
  sh[t] = tsum;
  __syncthreads();
  #pragma unroll
  for (int off=1; off<256; off<<=1){
    int x = (t>=off) ? sh[t-off] : 0;
    __syncthreads();
    sh[t] += x;
    __syncthreads();
  }
  if (t==255) blksum[blockIdx.x] = sh[255];
  int run = sh[t] - tsum;
  #pragma unroll
  for (int j=0;j<4;j++){ if (base+j < n) out[base+j] = run; run += v[j]; }
}

__global__ void k_scan2(int* __restrict__ blksum, int nb, int* __restrict__ total){
  if (threadIdx.x == 0){
    int run = 0;
    for (int i=0;i<nb;i++){ int v = blksum[i]; blksum[i] = run; run += v; }
    *total = run;
  }
}

__global__ void k_scan3(int* __restrict__ out, int* __restrict__ rowcur,
                        const int* __restrict__ blksum, const int* __restrict__ total,
                        int n){
  int i = blockIdx.x*256 + threadIdx.x;
  if (i < n){
    int r = out[i] + blksum[i >> 10];
    out[i] = r;
    rowcur[i] = r;
  }
  if (i == 0) out[n] = *total;
}

// zero only the pad slots (<=7 per node) instead of the whole colpk buffer
__global__ void k_pad(const int* __restrict__ cnt, const int* __restrict__ rowptr,
                      int2* __restrict__ colpk, int n){
  int v = blockIdx.x*256 + threadIdx.x;
  if (v < n){
    int p = rowptr[v] + cnt[v];
    int e = rowptr[v+1];
    for (; p < e; p++) colpk[p] = make_int2(0, 0);   // src=0, w=0.0f
  }
}

__global__ void k_fill(const int* __restrict__ src, const int* __restrict__ dst,
                       const float* __restrict__ dinv,
                       int* __restrict__ rowcur, int2* __restrict__ colpk, int E){
  int e = blockIdx.x*256 + threadIdx.x;
  if (e < E){
    int d = dst[e];
    int pos = atomicAdd(&rowcur[d], 1);
    int s = src[e];
    colpk[pos] = make_int2(s, __float_as_int(dinv[s]));
  }
}

__global__ void k_copyx(const float4* __restrict__ x, float* __restrict__ out, int n4){
  int i = blockIdx.x*256 + threadIdx.x;
  if (i < n4){
    int v = i >> 5, f4 = i & 31;
    ((float4*)(out + (size_t)v*512))[f4] = x[i];
  }
}

// H2[N][64] (packed bf16x2) = A[N,128](lda) @ W[128,128]  via mfma_f32_16x16x32_bf16.
// Block: 256 thr = 4 waves; 64 rows x 128 cols, K=128.
// LDS: A-tile [64][128] bf16 + W^T [128][128] bf16, both XOR-swizzled (G4).
__launch_bounds__(256)
__global__ void k_gemm(const float* __restrict__ A, int lda, const float* __restrict__ W,
                       unsigned* __restrict__ H2, int n){
  __shared__ unsigned short Al[64*128];    // 16 KB, swizzled [row][k]
  __shared__ unsigned short Wt[128*128];   // 32 KB, swizzled [ncol][k]
  const int t = threadIdx.x;

  // --- stage A tile (fp32 -> bf16), coalesced, swizzled ---
  {
    int row = t >> 2;                      // 0..63
    int q   = t & 3;                       // k chunk of 32
    int gr  = blockIdx.x*64 + row;
    if (gr > n-1) gr = n-1;
    const float4* src = (const float4*)(A + (size_t)gr*lda + q*32);
    unsigned short* dstb = Al + row*128;
    int swz = (row & 7) << 3;              // ushort-index swizzle (== byte ^ (row&7)<<4)
    #pragma unroll
    for (int c8=0; c8<4; c8++){
      float4 f0 = src[c8*2], f1 = src[c8*2+1];
      uint4 pk;
      pk.x = bf16rne(f0.x) | (bf16rne(f0.y)<<16);
      pk.y = bf16rne(f0.z) | (bf16rne(f0.w)<<16);
      pk.z = bf16rne(f1.x) | (bf16rne(f1.y)<<16);
      pk.w = bf16rne(f1.z) | (bf16rne(f1.w)<<16);
      int ke = q*32 + c8*8;
      *(uint4*)(dstb + (ke ^ swz)) = pk;
    }
  }
  // --- stage W^T (fp32 [k][n] -> bf16 [n][k]), coalesced reads, swizzled dword writes ---
  {
    int nn = t & 127;
    int kh = t >> 7;                       // 0/1
    int swz = (nn & 7) << 3;
    unsigned short* dstb = Wt + nn*128;
    #pragma unroll 4
    for (int i=0;i<32;i++){
      int k = (i*2 + kh)*2;                // even k
      float w0 = W[(size_t)k*128 + nn];
      float w1 = W[(size_t)(k+1)*128 + nn];
      *(unsigned*)(dstb + (k ^ swz)) = bf16rne(w0) | (bf16rne(w1)<<16);
    }
  }
  __syncthreads();

  const int w  = t >> 6;                   // wave 0..3 -> rows w*16..+15
  const int l  = t & 63;
  const int lo = l & 15, hi = l >> 4;

  // A frags: row = lo, k = kc*32 + hi*8 + j
  const unsigned short* arow = Al + (w*16 + lo)*128;
  const int aswz = ((w*16 + lo) & 7) << 3;
  short8v a[4];
  #pragma unroll
  for (int kc=0;kc<4;kc++){
    int ke = kc*32 + hi*8;
    a[kc] = *(const short8v*)(arow + (ke ^ aswz));
  }

  float4v acc[8];
  #pragma unroll
  for (int ct=0;ct<8;ct++) acc[ct] = (float4v)(0.f);

  #pragma unroll
  for (int ct=0;ct<8;ct++){
    int col = ct*16 + lo;
    const unsigned short* brow = Wt + col*128;
    int bswz = (col & 7) << 3;
    #pragma unroll
    for (int kc=0;kc<4;kc++){
      int ke = kc*32 + hi*8;
      short8v b = *(const short8v*)(brow + (ke ^ bswz));
      acc[ct] = __builtin_amdgcn_mfma_f32_16x16x32_bf16(a[kc], b, acc[ct], 0, 0, 0);
    }
  }

  // epilogue: D lane map col=l&15, row=(l>>4)*4+r; pack col pairs via shfl, store dwords
  const int rbase = blockIdx.x*64 + w*16;
  #pragma unroll
  for (int ct=0;ct<8;ct++){
    int col = ct*16 + lo;
    #pragma unroll
    for (int r=0;r<4;r++){
      unsigned bits  = bf16rne(acc[ct][r]);
      unsigned other = (unsigned)__shfl_xor((int)bits, 1, 64);
      int grow = rbase + hi*4 + r;
      if (!(l & 1) && grow < n)
        H2[(size_t)grow*64 + (col>>1)] = bits | (other<<16);
    }
  }
}

// Pull aggregation + fused BN partial stats. 1 wave per node-row, NPW nodes/wave.
// Per edge: 1 scalar int2 index load + 1 dword gather (256B/wave). No tail.
__launch_bounds__(256)
__global__ void k_agg(const unsigned* __restrict__ h2, const int* __restrict__ rowptr,
                      const int2* __restrict__ colpk, const float* __restrict__ dinv,
                      float* __restrict__ out, int colOff,
                      float* __restrict__ statrep, int n){
  __shared__ float red[4*256];
  const int lane = threadIdx.x & 63;
  const int wv   = threadIdx.x >> 6;
  const int v0   = (blockIdx.x*4 + wv) * NPW;
  float s0=0.f, s1=0.f, q0s=0.f, q1s=0.f;
  #pragma unroll 1
  for (int vi=0; vi<NPW; vi++){
    int v = v0 + vi;
    if (v < n){
      int j = rowptr[v], end = rowptr[v+1];
      float a0 = 0.f, a1 = 0.f;
      #pragma unroll 1
      for (; j < end; j += 8){
        int2 p0=colpk[j],   p1=colpk[j+1], p2=colpk[j+2], p3=colpk[j+3];
        int2 p4=colpk[j+4], p5=colpk[j+5], p6=colpk[j+6], p7=colpk[j+7];
        unsigned e0=h2[(size_t)p0.x*64+lane], e1=h2[(size_t)p1.x*64+lane];
        unsigned e2=h2[(size_t)p2.x*64+lane], e3=h2[(size_t)p3.x*64+lane];
        unsigned e4=h2[(size_t)p4.x*64+lane], e5=h2[(size_t)p5.x*64+lane];
        unsigned e6=h2[(size_t)p6.x*64+lane], e7=h2[(size_t)p7.x*64+lane];
        float w0=__int_as_float(p0.y), w1=__int_as_float(p1.y);
        float w2=__int_as_float(p2.y), w3=__int_as_float(p3.y);
        float w4=__int_as_float(p4.y), w5=__int_as_float(p5.y);
        float w6=__int_as_float(p6.y), w7=__int_as_float(p7.y);
        a0 = fmaf(w0, bflo(e0), a0);  a1 = fmaf(w0, bfhi(e0), a1);
        a0 = fmaf(w1, bflo(e1), a0);  a1 = fmaf(w1, bfhi(e1), a1);
        a0 = fmaf(w2, bflo(e2), a0);  a1 = fmaf(w2, bfhi(e2), a1);
        a0 = fmaf(w3, bflo(e3), a0);  a1 = fmaf(w3, bfhi(e3), a1);
        a0 = fmaf(w4, bflo(e4), a0);  a1 = fmaf(w4, bfhi(e4), a1);
        a0 = fmaf(w5, bflo(e5), a0);  a1 = fmaf(w5, bfhi(e5), a1);
        a0 = fmaf(w6, bflo(e6), a0);  a1 = fmaf(w6, bfhi(e6), a1);
        a0 = fmaf(w7, bflo(e7), a0);  a1 = fmaf(w7, bfhi(e7), a1);
      }
      float dv = dinv[v];
      unsigned qs = h2[(size_t)v*64 + lane];
      a0 = dv*(a0 + dv*bflo(qs));
      a1 = dv*(a1 + dv*bfhi(qs));
      *(float2*)(out + (size_t)v*512 + colOff + lane*2) = make_float2(a0, a1);
      s0 += a0; q0s = fmaf(a0,a0,q0s);
      s1 += a1; q1s = fmaf(a1,a1,q1s);
    }
  }
  // cross-wave reduce: red[wv][f]=sum, red[wv][128+f]=sumsq
  red[wv*256 + 2*lane]     = s0;
  red[wv*256 + 2*lane+1]   = s1;
  red[wv*256 + 128+2*lane]   = q0s;
  red[wv*256 + 128+2*lane+1] = q1s;
  __syncthreads();
  int t = threadIdx.x;
  float tot = red[t] + red[256+t] + red[512+t] + red[768+t];
  atomicAdd(&statrep[((blockIdx.x & 7)<<8) + t], tot);
}

// reduce 8 stat replicas -> scale/shift; re-zero replicas for next layer/call
__global__ void k_bnprep(float* __restrict__ statrep,
                         const float* __restrict__ gamma, const float* __restrict__ beta,
                         float* __restrict__ ss, int n){
  int f = threadIdx.x;
  if (f < 128){
    float s = 0.f, s2 = 0.f;
    #pragma unroll
    for (int r=0;r<8;r++){
      s  += statrep[r*256 + f];
      s2 += statrep[r*256 + 128 + f];
    }
    #pragma unroll
    for (int r=0;r<8;r++){
      statrep[r*256 + f] = 0.f;
      statrep[r*256 + 128 + f] = 0.f;
    }
    float invn = 1.0f / (float)n;
    float mu  = s * invn;
    float var = s2 * invn - mu*mu;
    float rs  = rsqrtf(var + EPS_BN);
    float sc  = gamma[f] * rs;
    ss[f]       = sc;
    ss[128 + f] = beta[f] - mu * sc;
  }
}

__global__ void k_bnrelu(float* __restrict__ out, int colOff,
                         const float* __restrict__ ss, int n){
  int i = blockIdx.x*256 + threadIdx.x;
  if (i >= n*32) return;
  int v = i >> 5, c = i & 31;
  int f = c*4;
  float4* p = (float4*)(out + (size_t)v*512 + colOff);
  float4 val = p[c];
  val.x = fmaxf(fmaf(val.x, ss[f+0], ss[128+f+0]), 0.f);
  val.y = fmaxf(fmaf(val.y, ss[f+1], ss[128+f+1]), 0.f);
  val.z = fmaxf(fmaf(val.z, ss[f+2], ss[128+f+2]), 0.f);
  val.w = fmaxf(fmaf(val.w, ss[f+3], ss[128+f+3]), 0.f);
  p[c] = val;
}

extern "C" void kernel_launch(void* const* d_in, const int* in_sizes, int n_in,
                              void* d_out, int out_size, void* d_ws, size_t ws_size,
                              hipStream_t stream){
  const float* x      = (const float*)d_in[0];
  const int*   ei     = (const int*)d_in[1];
  const float* Ws     = (const float*)d_in[2];
  // d_in[3] = bs: cancels exactly in BatchNorm
  const float* gammas = (const float*)d_in[4];
  const float* betas  = (const float*)d_in[5];
  const int N = in_sizes[0] / 128;
  const int E = in_sizes[1] / 2;
  float* out = (float*)d_out;

  const int EPADCAP = E + 7*N + 8;   // padded-CSR capacity

  char* w = (char*)d_ws;
  auto alloc = [&](size_t bytes)->char*{
    char* p = w; w += (bytes + 255) & ~(size_t)255; return p;
  };
  int*      cnt     = (int*)     alloc((size_t)N*4);
  float*    statrep = (float*)   alloc(8*256*4);       // adjacent to cnt for one-shot zero
  int*      rowptr  = (int*)     alloc((size_t)(N+1)*4);
  int*      rowcur  = (int*)     alloc((size_t)N*4);
  int*      blksum  = (int*)     alloc(64*4);
  int*      total   = (int*)     alloc(64);
  int2*     colpk   = (int2*)    alloc((size_t)EPADCAP*8);
  float*    dinv    = (float*)   alloc((size_t)N*4);
  float*    ss      = (float*)   alloc(256*4);
  unsigned* h2      = (unsigned*)alloc((size_t)N*64*4);

  const int* srcArr = ei;
  const int* dstArr = ei + E;

  const int nbN = (N + 255)/256;
  const int nbE = (E + 255)/256;
  const int nscan = (N + 1023)/1024;
  // zero cnt + (alignment gap) + statrep in one launch
  const int nz = (int)(((char*)statrep - (char*)cnt)/4) + 8*256;

  k_zero_i32<<<(nz + 255)/256,256,0,stream>>>(cnt, nz);
  k_count<<<nbE,256,0,stream>>>(dstArr, cnt, E);
  k_scan1<<<nscan,256,0,stream>>>(cnt, rowptr, blksum, dinv, N);
  k_scan2<<<1,64,0,stream>>>(blksum, nscan, total);
  k_scan3<<<nbN,256,0,stream>>>(rowptr, rowcur, blksum, total, N);
  k_pad<<<nbN,256,0,stream>>>(cnt, rowptr, colpk, N);
  k_fill<<<nbE,256,0,stream>>>(srcArr, dstArr, dinv, rowcur, colpk, E);
  k_copyx<<<(N*32 + 255)/256,256,0,stream>>>((const float4*)x, out, N*32);

  for (int l=0; l<3; l++){
    const float* A = (l == 0) ? x : (out + l*128);
    int lda = (l == 0) ? 128 : 512;
    k_gemm<<<(N + 63)/64,256,0,stream>>>(A, lda, Ws + (size_t)l*128*128, h2, N);
    k_agg<<<(N + 4*NPW-1)/(4*NPW),256,0,stream>>>(h2, rowptr, colpk, dinv, out,
                                                  (l+1)*128, statrep, N);
    k_bnprep<<<1,128,0,stream>>>(statrep, gammas + l*128, betas + l*128, ss, N);
    k_bnrelu<<<((N*32) + 255)/256,256,0,stream>>>(out, (l+1)*128, ss, N);
  }
}